// Round 27
// baseline (397.329 us; speedup 1.0000x reference)
//
#include <hip/hip_runtime.h>
#include <math.h>

#define N      8192
#define GC     32                    // grid cells per axis
#define NCELL  (GC * GC * GC)        // 32768 cells per cloud
#define CAP    64                    // bucket capacity (Poisson(12) max ~35)
#define GLO    (-4.5f)
#define CS     (9.0f / GC)           // 0.28125 cell size
#define INVCS  (GC / 9.0f)
#define BBLK   256
#define QB     256
#define RPQ    8                     // lanes per query
#define QBLOCKS (2 * N * RPQ / QB)   // 512 query blocks (0-255 dir1, 256-511 dir2)

__device__ __forceinline__ int cellc(float v) {
    return min(max((int)floorf((v - GLO) * INVCS), 0), GC - 1);
}

// ------------------------------------------------------------------- bin ----
// Scatter each point into its cell bucket. atomicAdd slot order varies run
// to run, but min over the bucket SET is order-independent -> deterministic.
__global__ __launch_bounds__(BBLK) void chamfer_bin_kernel(
        const float* __restrict__ tgt, const float* __restrict__ outp,
        unsigned* __restrict__ cnt, float4* __restrict__ buck) {
    int i = blockIdx.x * BBLK + (int)threadIdx.x;   // 0 .. 2N-1
    const float* src = (i < N) ? tgt : outp;
    int k = (i < N) ? i : (i - N);
    int gb = (i < N) ? 0 : NCELL;                   // target grid | output grid
    float x = src[3 * k + 0];
    float y = src[3 * k + 1];
    float z = src[3 * k + 2];
    int cell = ((cellc(z) * GC + cellc(y)) * GC + cellc(x)) + gb;
    unsigned pos = atomicAdd(&cnt[cell], 1u);
    if (pos < CAP) buck[(size_t)cell * CAP + pos] = make_float4(x, y, z, 0.0f);
}

// ----------------------------------------------------------------- query ----
// Exact grid NN: 8 lanes per query. Fast path: 3x3x3 box with all 27 cell
// counts BATCH-loaded (independent gathers, one wait). Termination: after
// examining the Chebyshev-k box, any unexamined point is >= dist(q, box
// exterior) away; clamped outliers lie OUTWARD of their border cell, which
// only strengthens the bound -> exact result. Rare queries expand shells.
__global__ __launch_bounds__(QB) void chamfer_query_kernel(
        const float* __restrict__ tgt, const float* __restrict__ outp,
        const unsigned* __restrict__ cnt, const float4* __restrict__ buck,
        float* __restrict__ bsum) {
    __shared__ float sh[QB / 64];
    int tid = (int)threadIdx.x;
    int r   = tid & (RPQ - 1);
    int qi  = (int)blockIdx.x * (QB / RPQ) + (tid >> 3);   // 0 .. 16383
    int gb  = (qi < N) ? NCELL : 0;       // search the OTHER cloud's grid
    int k0  = (qi < N) ? qi : (qi - N);
    const float* qsrc = (qi < N) ? tgt : outp;
    float qx = qsrc[3 * k0 + 0];
    float qy = qsrc[3 * k0 + 1];
    float qz = qsrc[3 * k0 + 2];
    int cx = cellc(qx), cy = cellc(qy), cz = cellc(qz);

    float best = 1e30f;

    // fast path: batch the 27 cell counts (one latency wait), then stream
    unsigned ccnt[27];
    int      cbase[27];
    #pragma unroll
    for (int m = 0; m < 27; ++m) {
        int dx = m % 3 - 1, dy = (m / 3) % 3 - 1, dz = m / 9 - 1;
        int x = cx + dx, y = cy + dy, z = cz + dz;
        bool ok = (unsigned)x < GC && (unsigned)y < GC && (unsigned)z < GC;
        int cell = (((ok ? z : 0) * GC + (ok ? y : 0)) * GC + (ok ? x : 0)) + gb;
        ccnt[m]  = ok ? cnt[cell] : 0u;
        cbase[m] = cell * CAP;
    }
    #pragma unroll
    for (int m = 0; m < 27; ++m) {
        unsigned c = min(ccnt[m], (unsigned)CAP);
        const float4* bp = buck + (size_t)cbase[m];
        for (unsigned j = r; j < c; j += RPQ) {
            float4 p = bp[j];
            float dx = qx - p.x, dy = qy - p.y, dz = qz - p.z;
            best = fminf(best, fmaf(dx, dx, fmaf(dy, dy, dz * dz)));
        }
    }
    float g = fminf(best, __shfl_xor(best, 1, 64));
    g = fminf(g, __shfl_xor(g, 2, 64));
    g = fminf(g, __shfl_xor(g, 4, 64));

    int x0 = max(cx - 1, 0), x1 = min(cx + 1, GC - 1);
    int y0 = max(cy - 1, 0), y1 = min(cy + 1, GC - 1);
    int z0 = max(cz - 1, 0), z1 = min(cz + 1, GC - 1);
    float bnd = 1e30f;
    if (x0 > 0)      bnd = fminf(bnd, qx - (GLO + x0 * CS));
    if (x1 < GC - 1) bnd = fminf(bnd, (GLO + (x1 + 1) * CS) - qx);
    if (y0 > 0)      bnd = fminf(bnd, qy - (GLO + y0 * CS));
    if (y1 < GC - 1) bnd = fminf(bnd, (GLO + (y1 + 1) * CS) - qy);
    if (z0 > 0)      bnd = fminf(bnd, qz - (GLO + z0 * CS));
    if (z1 < GC - 1) bnd = fminf(bnd, (GLO + (z1 + 1) * CS) - qz);

    if (!(g <= bnd * bnd)) {
        // general expanding shells (rare: sparse-region / outlier queries)
        for (int k = 2; k < GC; ++k) {
            x0 = max(cx - k, 0); x1 = min(cx + k, GC - 1);
            y0 = max(cy - k, 0); y1 = min(cy + k, GC - 1);
            z0 = max(cz - k, 0); z1 = min(cz + k, GC - 1);
            for (int z = z0; z <= z1; ++z)
            for (int y = y0; y <= y1; ++y)
            for (int x = x0; x <= x1; ++x) {
                int ch = max(abs(x - cx), max(abs(y - cy), abs(z - cz)));
                if (ch != k) continue;                 // shell only
                int cell = ((z * GC + y) * GC + x) + gb;
                unsigned c = min(cnt[cell], (unsigned)CAP);
                const float4* bp = buck + (size_t)cell * CAP;
                for (unsigned j = r; j < c; j += RPQ) {
                    float4 p = bp[j];
                    float ddx = qx - p.x, ddy = qy - p.y, ddz = qz - p.z;
                    best = fminf(best, fmaf(ddx, ddx, fmaf(ddy, ddy, ddz * ddz)));
                }
            }
            g = fminf(best, __shfl_xor(best, 1, 64));
            g = fminf(g, __shfl_xor(g, 2, 64));
            g = fminf(g, __shfl_xor(g, 4, 64));
            bnd = 1e30f;
            if (x0 > 0)      bnd = fminf(bnd, qx - (GLO + x0 * CS));
            if (x1 < GC - 1) bnd = fminf(bnd, (GLO + (x1 + 1) * CS) - qx);
            if (y0 > 0)      bnd = fminf(bnd, qy - (GLO + y0 * CS));
            if (y1 < GC - 1) bnd = fminf(bnd, (GLO + (y1 + 1) * CS) - qy);
            if (z0 > 0)      bnd = fminf(bnd, qz - (GLO + z0 * CS));
            if (z1 < GC - 1) bnd = fminf(bnd, (GLO + (z1 + 1) * CS) - qz);
            if (g <= bnd * bnd) break;   // bnd=1e30 once box covers grid
        }
    }

    // deterministic block partial: lane r==0 contributes sqrt(min)
    float sq = (r == 0) ? sqrtf(g) : 0.0f;
    #pragma unroll
    for (int off = 32; off > 0; off >>= 1) sq += __shfl_down(sq, off, 64);
    int wid = tid >> 6, lane = tid & 63;
    if (lane == 0) sh[wid] = sq;
    __syncthreads();
    if (tid == 0) {
        float b = 0.0f;
        #pragma unroll
        for (int w = 0; w < QB / 64; ++w) b += sh[w];
        bsum[blockIdx.x] = b;
    }
}

// ----------------------------------------------------------------- final ----
__global__ __launch_bounds__(256) void chamfer_final_kernel(
        const float* __restrict__ bsum,
        const int* __restrict__ curp, const int* __restrict__ subp,
        float* __restrict__ out) {
    __shared__ float sh1[4], sh2[4];
    int t = (int)threadIdx.x;               // 256 threads
    float a = bsum[t];                      // dir1 partials (blocks 0..255)
    float b = bsum[256 + t];                // dir2 partials (blocks 256..511)
    #pragma unroll
    for (int off = 32; off > 0; off >>= 1) {
        a += __shfl_down(a, off, 64);
        b += __shfl_down(b, off, 64);
    }
    int wid = t >> 6, lane = t & 63;
    if (lane == 0) { sh1[wid] = a; sh2[wid] = b; }
    __syncthreads();
    if (t == 0) {
        float s1 = sh1[0] + sh1[1] + sh1[2] + sh1[3];
        float s2 = sh2[0] + sh2[1] + sh2[2] + sh2[3];
        int e = curp[0] / subp[0];
        double scale = 10.0 / pow(0.99, (double)e);
        out[0] = (float)((((double)s1 + (double)s2) / (double)N) * 0.5 * scale);
    }
}

// ---------------------------------------------------------------- launch ----
extern "C" void kernel_launch(void* const* d_in, const int* in_sizes, int n_in,
                              void* d_out, int out_size, void* d_ws, size_t ws_size,
                              hipStream_t stream) {
    const float* target = (const float*)d_in[0];   // (1, 8192, 3) f32
    const float* output = (const float*)d_in[1];   // (1, 8192, 3) f32
    const int*   curp   = (const int*)d_in[2];
    const int*   subp   = (const int*)d_in[3];
    float* out = (float*)d_out;

    // ws: buck float4[2*NCELL*CAP] (64MB) | cnt u32[2*NCELL] (256KB) | bsum[512]
    float4*   buck = (float4*)d_ws;
    unsigned* cnt  = (unsigned*)(buck + (size_t)2 * NCELL * CAP);
    float*    bsum = (float*)(cnt + 2 * NCELL);

    hipMemsetAsync(cnt, 0, 2 * NCELL * sizeof(unsigned), stream);
    chamfer_bin_kernel<<<2 * N / BBLK, BBLK, 0, stream>>>(target, output, cnt, buck);
    chamfer_query_kernel<<<QBLOCKS, QB, 0, stream>>>(target, output, cnt, buck, bsum);
    chamfer_final_kernel<<<1, 256, 0, stream>>>(bsum, curp, subp, out);
}